// Round 4
// baseline (165.039 us; speedup 1.0000x reference)
//
#include <hip/hip_runtime.h>

#define NN 50000
#define TT 12
#define QQ 3
#define HH 64
#define KK 32
#define TQ 36   // T*Q
#define NLEV 4

// ---------------------------------------------------------------------------
// Projection: out[r][q] = sum_h gnn[r][h] * w[h][q] + b[q],  r in [0, N*T).
// Also writes a pristine copy of the projection (race-avoidance source for
// same-level gathers in the level kernels).
// ---------------------------------------------------------------------------
__global__ __launch_bounds__(256) void proj_kernel(
    const float* __restrict__ gnn, const float* __restrict__ w,
    const float* __restrict__ b, float* __restrict__ out,
    float* __restrict__ copy, int nrows)
{
    const int lane = threadIdx.x & 63;
    const int sub  = lane & 15;          // position within 16-lane row-group
    const int h0   = sub * 4;

    float wreg[4][3];
#pragma unroll
    for (int j = 0; j < 4; ++j)
#pragma unroll
        for (int q = 0; q < 3; ++q)
            wreg[j][q] = w[(h0 + j) * 3 + q];
    const float b0 = b[0], b1 = b[1], b2 = b[2];

    const int gwave  = (blockIdx.x * blockDim.x + threadIdx.x) >> 6;
    const int nwaves = (gridDim.x * blockDim.x) >> 6;
    const int nquads = nrows >> 2;

    for (int quad = gwave; quad < nquads; quad += nwaves) {
        const float4 g = *reinterpret_cast<const float4*>(gnn + (size_t)quad * 256 + lane * 4);
        float a0 = g.x * wreg[0][0] + g.y * wreg[1][0] + g.z * wreg[2][0] + g.w * wreg[3][0];
        float a1 = g.x * wreg[0][1] + g.y * wreg[1][1] + g.z * wreg[2][1] + g.w * wreg[3][1];
        float a2 = g.x * wreg[0][2] + g.y * wreg[1][2] + g.z * wreg[2][2] + g.w * wreg[3][2];
#pragma unroll
        for (int off = 8; off > 0; off >>= 1) {
            a0 += __shfl_down(a0, off);
            a1 += __shfl_down(a1, off);
            a2 += __shfl_down(a2, off);
        }
        if (sub == 0) {
            const int row = quad * 4 + (lane >> 4);
            out[row * 3 + 0] = a0 + b0;
            out[row * 3 + 1] = a1 + b1;
            out[row * 3 + 2] = a2 + b2;
            copy[row * 3 + 0] = a0 + b0;
            copy[row * 3 + 1] = a1 + b1;
            copy[row * 3 + 2] = a2 + b2;
        }
    }
}

// ---------------------------------------------------------------------------
// Per-level node lists via wave-aggregated atomics (<=4 atomics per wave).
// ---------------------------------------------------------------------------
__global__ __launch_bounds__(256) void compact_kernel(
    const int* __restrict__ lvl, int* __restrict__ counts,
    int* __restrict__ lists)
{
    const int i    = blockIdx.x * blockDim.x + threadIdx.x;
    const int lane = threadIdx.x & 63;
    const int l    = (i < NN) ? lvl[i] : -1;
    const unsigned long long below = (lane == 63) ? ~0ull >> 1
                                   : ((1ull << lane) - 1);
#pragma unroll
    for (int lev = 0; lev < NLEV; ++lev) {
        const unsigned long long m = __ballot(l == lev);
        if (m == 0ull) continue;
        const int leader = __ffsll((long long)m) - 1;
        int base = 0;
        if (lane == leader) base = atomicAdd(&counts[lev], __popcll(m));
        base = __shfl(base, leader);
        if (l == lev) {
            lists[lev * NN + base + __popcll(m & below)] = i;
        }
    }
}

// ---------------------------------------------------------------------------
// One level, direct-write: thread = (list-index, t). Computes all Q=3 outputs.
//   out[node][t][:] = (sum_k src[key][t][:] * sc[key][t]) / sc[node][t]
// where src = pristine `copy` iff lvl[key]==level (that node's pre-level value
// is its projection value — it was never updated before its own level), else
// the live `out`. Eliminates the tmp+scatter round trip.
// ---------------------------------------------------------------------------
__global__ __launch_bounds__(256) void agg_kernel(
    const float* __restrict__ copy, const float* __restrict__ scaler,
    const int* __restrict__ keybom, const int* __restrict__ lvl,
    const int* __restrict__ lists, const int* __restrict__ counts,
    float* out, int level)
{
    const int idx = blockIdx.x * blockDim.x + threadIdx.x;
    const int li  = idx / TT;
    const int t   = idx - li * TT;
    if (li >= counts[level]) return;
    const int node = lists[level * NN + li];

    const int* kb = keybom + (size_t)node * KK;
    float a0 = 0.0f, a1 = 0.0f, a2 = 0.0f;
#pragma unroll 4
    for (int k = 0; k < KK; ++k) {
        const int key = kb[k];
        if (key < 0) continue;
        const float s = scaler[key * TT + t];
        const float* src = (lvl[key] == level) ? copy : out;
        const float* p = src + (size_t)key * TQ + t * QQ;
        a0 += p[0] * s;
        a1 += p[1] * s;
        a2 += p[2] * s;
    }
    const float sn = scaler[node * TT + t];
    float* o = out + (size_t)node * TQ + t * QQ;
    o[0] = a0 / sn;
    o[1] = a1 / sn;
    o[2] = a2 / sn;
}

extern "C" void kernel_launch(void* const* d_in, const int* in_sizes, int n_in,
                              void* d_out, int out_size, void* d_ws, size_t ws_size,
                              hipStream_t stream)
{
    const float* gnn    = (const float*)d_in[0];
    const float* w      = (const float*)d_in[1];
    const float* b      = (const float*)d_in[2];
    const float* scaler = (const float*)d_in[3];
    const int*   keybom = (const int*)d_in[4];
    const int*   lvl    = (const int*)d_in[5];
    float* out = (float*)d_out;

    char* ws = (char*)d_ws;
    int*   counts = (int*)ws;                                  // 4 ints
    int*   lists  = (int*)(ws + 16);                           // 4*NN ints
    float* copy   = (float*)(ws + 16 + (size_t)4 * NN * 4);    // NN*TQ floats

    hipMemsetAsync(counts, 0, 16, stream);

    const int nrows = NN * TT;
    proj_kernel<<<2048, 256, 0, stream>>>(gnn, w, b, out, copy, nrows);
    compact_kernel<<<(NN + 255) / 256, 256, 0, stream>>>(lvl, counts, lists);

    const int blocks = (NN * TT + 255) / 256;   // worst case: all nodes one level
    for (int level = 1; level < NLEV; ++level) {
        agg_kernel<<<blocks, 256, 0, stream>>>(copy, scaler, keybom, lvl,
                                               lists, counts, out, level);
    }
}